// Round 3
// baseline (293.104 us; speedup 1.0000x reference)
//
#include <hip/hip_runtime.h>
#include <hip/hip_bf16.h>
#include <cstdint>

typedef __bf16 bf16_t;
typedef __bf16 bf16x8 __attribute__((ext_vector_type(8)));
typedef float  floatx4 __attribute__((ext_vector_type(4)));

typedef const __attribute__((address_space(1))) unsigned int* gptr_t;
typedef __attribute__((address_space(3))) unsigned int* lptr_t;

static __device__ __forceinline__ void gl2lds16(const bf16_t* g, bf16_t* l) {
  __builtin_amdgcn_global_load_lds((gptr_t)g, (lptr_t)l, 16, 0, 0);
}

#define BAR()     asm volatile("s_barrier" ::: "memory")
#define VMW(NSTR) asm volatile("s_waitcnt vmcnt(" NSTR ")" ::: "memory")
#define SB()      __builtin_amdgcn_sched_barrier(0)

// 16-MFMA cluster: acc[R..R+3][0..3] += A[f] x B[j]; setprio wrap (T5).
static __device__ __forceinline__ void mm16(floatx4 (&acc)[8][4], int R,
                                            const bf16x8 (&A)[4],
                                            const bf16x8 (&B)[4]) {
  __builtin_amdgcn_s_setprio(1);
#pragma unroll
  for (int f = 0; f < 4; ++f)
#pragma unroll
    for (int j = 0; j < 4; ++j)
      acc[R + f][j] = __builtin_amdgcn_mfma_f32_16x16x32_bf16(A[f], B[j],
                                                              acc[R + f][j],
                                                              0, 0, 0);
  __builtin_amdgcn_s_setprio(0);
}

// ---------------------------------------------------------------------------
// ROUND-12: 256x256 8-phase GEMM + SCHED_BARRIER(0) REGION PINS.
// Round-10/11 both ran at 666 TF = the degenerate 2-phase rate (m248): the
// LLVM scheduler was sinking ds_reads to their consumers and floating MFMAs
// across the raw s_barriers ("memory" clobber does not order register-only
// MFMA, rule #18), collapsing the written 8-phase interleave. Fix = pin each
// phase's two regions with __builtin_amdgcn_sched_barrier(0):
//   [ds_reads(p+1) | STAGE] SB BAR [mm16(p)] SB (VMW) BAR
// so reads issue early (service overlaps MFMA), stages stay in-phase, and
// the counted auto-lgkmcnt the compiler inserts before mm16 skips the
// in-flight prefetch. Everything else unchanged from round-11:
//  * 8 distinct 16KiB LDS arrays ({buf}x{A,B}x{khalf}), unroll-by-2
//  * prefetch-ahead register pipeline (mm16(p) consumes reads of p-1)
//  * counted VMW(8) at ph0/ph2 ends (overwrite-vs-read proof in round-11)
//  * panel-walking XCD swizzle (FETCH 41.9MB verified round-11)
// Geometry: 8 waves (2Mx4N), per-wave 128x64, acc[8][4], BK=64 as 2 K-halves,
// XOR chunk swizzle (involution; 0 main-loop bank conflicts, round-9).
// ---------------------------------------------------------------------------
template<int HAS_BIAS, int EXP_COLSUM, int SPLIT3>
__global__ __launch_bounds__(512, 2)
void gemm256(const bf16_t* __restrict__ A, const bf16_t* __restrict__ Bt,
             void* __restrict__ Cv,
             const float* __restrict__ b0, const float* __restrict__ b1,
             const float* __restrict__ b2,
             float* __restrict__ L,
             int M, int N, int K, int ldC, float alpha,
             long sA, long sB, long sC,
             long co0, long co1, long co2,
             int mbShift, int ldTv, long sTv)
{
  __shared__ __align__(16) bf16_t sA0k0[8192];
  __shared__ __align__(16) bf16_t sA0k1[8192];
  __shared__ __align__(16) bf16_t sB0k0[8192];
  __shared__ __align__(16) bf16_t sB0k1[8192];
  __shared__ __align__(16) bf16_t sA1k0[8192];
  __shared__ __align__(16) bf16_t sA1k1[8192];
  __shared__ __align__(16) bf16_t sB1k0[8192];
  __shared__ __align__(16) bf16_t sB1k1[8192];

  const int bz = blockIdx.z;
  A  += bz * sA;
  Bt += bz * sB;

  // XCD-aware swizzle v2 (panel-walking)
  int bx = blockIdx.x, by = blockIdx.y;
  {
    const int gx = gridDim.x, gy = gridDim.y;
    const int nb = gx * gy;
    if (((nb & 7) == 0) && ((gx & 3) == 0) && ((gy & 7) == 0)) {
      const int id   = bx + gx * by;
      const int xcd  = id & 7;
      const int o    = id >> 3;
      const int rows = gy >> 3;
      const int pw   = rows << 2;
      const int p    = o / pw;
      const int r    = o - p * pw;
      by = xcd * rows + (r >> 2);
      bx = (p << 2) + (r & 3);
    }
  }

  const int gn0 = bx * 256;
  const int m0  = by * 256;
  const int tid  = threadIdx.x;
  const int lane = tid & 63;
  const int wave = tid >> 6;
  const int wm   = wave >> 2;      // 0..1  (M half)
  const int wn   = wave & 3;       // 0..3  (N quarter)
  const int lm   = lane & 15;
  const int quad = lane >> 4;

  int n0 = gn0, which = 0;
  bf16_t* Cb = (bf16_t*)Cv;
  const float* bias = b0;
  if (SPLIT3) {
    which = gn0 >> 10;
    n0 = gn0 & 1023;
    Cb += (which == 0) ? co0 : (which == 1) ? co1 : co2;
    bias = (which == 0) ? b0 : (which == 1) ? b1 : b2;
  }

  // staging: thread tid -> row tid>>2 (+128 for 2nd load), LDS chunk tid&3;
  // global chunk pre-swizzled with row bits 1-2 (involution).
  const int srow = tid >> 2;
  const int scol = ((tid ^ (tid >> 3)) & 3) * 8;
  const bf16_t* pA = A  + (long)(m0  + srow) * K + scol;
  const bf16_t* pB = Bt + (long)(gn0 + srow) * K + scol;

  const int nt = K >> 6;            // K-tiles of 64 (even, >= 4)

  // fragment-read element offsets (chunk XOR matches staging involution)
  const int csz_e = ((quad ^ (lm >> 1)) & 3) * 8;
  const int aoffe = (wm * 128 + lm) * 32 + csz_e;
  const int boffe = (wn * 64  + lm) * 32 + csz_e;

#define STG(DST, GP) do { \
    gl2lds16((GP), &DST[tid * 8]); \
    gl2lds16((GP) + (long)128 * K, &DST[tid * 8 + 4096]); } while (0)

#define LD4A(DSTR, ARR, FB) do { \
    DSTR[0] = *(const bf16x8*)&ARR[aoffe + ((FB) + 0) * 512]; \
    DSTR[1] = *(const bf16x8*)&ARR[aoffe + ((FB) + 1) * 512]; \
    DSTR[2] = *(const bf16x8*)&ARR[aoffe + ((FB) + 2) * 512]; \
    DSTR[3] = *(const bf16x8*)&ARR[aoffe + ((FB) + 3) * 512]; } while (0)

#define LD4B(DSTR, ARR) do { \
    DSTR[0] = *(const bf16x8*)&ARR[boffe + 0 * 512]; \
    DSTR[1] = *(const bf16x8*)&ARR[boffe + 1 * 512]; \
    DSTR[2] = *(const bf16x8*)&ARR[boffe + 2 * 512]; \
    DSTR[3] = *(const bf16x8*)&ARR[boffe + 3 * 512]; } while (0)

  // One K-tile = 4 phases. Entering ph0: ra=A03.k0(t), rb=B.k0(t) prefetched
  // in previous tile's ph3. Stage plan per phase: ph0 -> other.A.k1 (t+1);
  // ph1 -> this.B.k0 (t+2); ph2 -> this.A.k0 (t+2); ph3 -> this.B.k1 (t+2).
  // Region pins (SB) keep emitted order == written order.
#define TILE8(AK0, AK1, BK0, BK1, OAK0, OAK1, OBK0, T, S0, S1, S2, S3, W0S, W2S, PF3) do { \
    /* ph0: prefetch A47.k0; MFMA A03.k0 x B.k0 */ \
    LD4A(qa, AK0, 4); \
    if (S0) STG(OAK1, pA + ((T) + 1) * 64 + 32); \
    SB(); BAR(); \
    mm16(acc, 0, ra, rb); \
    SB(); VMW(W0S); BAR(); \
    /* ph1: prefetch B.k1 + A03.k1; MFMA A47.k0 x B.k0 */ \
    LD4B(sb, BK1); LD4A(sa, AK1, 0); \
    if (S1) STG(BK0, pB + ((T) + 2) * 64); \
    SB(); BAR(); \
    mm16(acc, 4, qa, rb); \
    SB(); BAR(); \
    /* ph2: prefetch A47.k1; MFMA A03.k1 x B.k1 */ \
    LD4A(qa, AK1, 4); \
    if (S2) STG(AK0, pA + ((T) + 2) * 64); \
    SB(); BAR(); \
    mm16(acc, 0, sa, sb); \
    SB(); VMW(W2S); BAR(); \
    /* ph3: prefetch next tile's B.k0 + A03.k0; MFMA A47.k1 x B.k1 */ \
    if (PF3) { LD4B(rb, OBK0); LD4A(ra, OAK0, 0); } \
    if (S3) STG(BK1, pB + ((T) + 2) * 64 + 32); \
    SB(); BAR(); \
    mm16(acc, 4, qa, sb); \
    SB(); BAR(); \
  } while (0)

  floatx4 acc[8][4];
#pragma unroll
  for (int f = 0; f < 8; ++f)
#pragma unroll
    for (int j = 0; j < 4; ++j)
      acc[f][j] = (floatx4)(0.f);

  bf16x8 ra[4], rb[4], qa[4], sa[4], sb[4];

  // prologue: stage halves s=0..6 in s-order; VMW(10) -> s=0,1 landed for
  // every wave before its BAR, so post-BAR all contributions are visible.
  STG(sB0k0, pB);            // s=0
  STG(sA0k0, pA);            // s=1
  STG(sB0k1, pB + 32);       // s=2
  STG(sA0k1, pA + 32);       // s=3
  STG(sB1k0, pB + 64);       // s=4
  STG(sA1k0, pA + 64);       // s=5
  STG(sB1k1, pB + 96);       // s=6
  VMW("10"); BAR();
  LD4B(rb, sB0k0);
  LD4A(ra, sA0k0, 0);
  SB();

  const int npair = nt >> 1;
  for (int p = 0; p < npair - 1; ++p) {
    const int t0 = 2 * p;
    TILE8(sA0k0, sA0k1, sB0k0, sB0k1, sA1k0, sA1k1, sB1k0, t0,     1, 1, 1, 1, "8", "8", 1);
    TILE8(sA1k0, sA1k1, sB1k0, sB1k1, sA0k0, sA0k1, sB0k0, t0 + 1, 1, 1, 1, 1, "8", "8", 1);
  }
  // tail pair: tile nt-2 stages only its ph0 half; tile nt-1 stages nothing.
  TILE8(sA0k0, sA0k1, sB0k0, sB0k1, sA1k0, sA1k1, sB1k0, nt - 2, 1, 0, 0, 0, "8", "4", 1);
  TILE8(sA1k0, sA1k1, sB1k0, sB1k1, sA0k0, sA0k1, sB0k0, nt - 1, 0, 0, 0, 0, "0", "0", 0);

  // ---------------- epilogue (C/D layout: col=lm, row=quad*4+r) ------------
  __syncthreads();
  const int r8 = lane >> 3;
  const int c8 = lane & 7;

  if (SPLIT3 && which == 2) {
    // transposed store: Vt[b][d][s]; per-wave scratch [16][144] = 2304 elems
    bf16_t* myT = (wave < 3) ? (sA0k0 + wave * 2304)
                : (wave < 6) ? (sA0k1 + (wave - 3) * 2304)
                             : (sB0k0 + (wave - 6) * 2304);
    const int b  = m0 >> mbShift;
    const int s0 = m0 & ((1 << mbShift) - 1);
#pragma unroll
    for (int j = 0; j < 4; ++j) {
      const float bv = HAS_BIAS ? bias[n0 + wn * 64 + j * 16 + lm] : 0.f;
#pragma unroll
      for (int f = 0; f < 8; ++f)
#pragma unroll
        for (int r = 0; r < 4; ++r)
          myT[lm * 144 + f * 16 + quad * 4 + r] = (bf16_t)(acc[f][j][r] + bv);
      // per-wave region + in-order DS pipe: no barrier needed
#pragma unroll
      for (int t2 = 0; t2 < 4; ++t2) {
        const int dr = (t2 & 1) * 8 + r8;
        const int ck = (t2 >> 1) * 8 + c8;
        const bf16x8 vv = *(const bf16x8*)&myT[dr * 144 + ck * 8];
        *(bf16x8*)&Cb[(long)b * sTv + (long)(n0 + wn * 64 + j * 16 + dr) * ldTv
                      + s0 + wm * 128 + ck * 8] = vv;
      }
    }
  } else {
    // per-wave scratch [16][68] = 1088 elems
    bf16_t* myEp = (wave < 7) ? (sA0k0 + wave * 1088) : sA0k1;
    float csum[4] = {0.f, 0.f, 0.f, 0.f};
    float bv[4];
#pragma unroll
    for (int j = 0; j < 4; ++j)
      bv[j] = HAS_BIAS ? bias[n0 + wn * 64 + j * 16 + lm] : 0.f;
#pragma unroll
    for (int f = 0; f < 8; ++f) {
#pragma unroll
      for (int j = 0; j < 4; ++j)
#pragma unroll
        for (int r = 0; r < 4; ++r) {
          float v = acc[f][j][r];
          if (EXP_COLSUM) { v = __expf(alpha * v); csum[j] += v; }
          v += bv[j];
          myEp[(quad * 4 + r) * 68 + j * 16 + lm] = (bf16_t)v;
        }
#pragma unroll
      for (int t2 = 0; t2 < 2; ++t2) {
        const int row = t2 * 8 + r8;
        const bf16x8 vv = *(const bf16x8*)&myEp[row * 68 + c8 * 8];
        *(bf16x8*)&Cb[bz * sC + (long)(m0 + wm * 128 + f * 16 + row) * ldC
                      + n0 + wn * 64 + c8 * 8] = vv;
      }
    }
    if (EXP_COLSUM) {
#pragma unroll
      for (int j = 0; j < 4; ++j) {
        float v = csum[j];
        v += __shfl_xor(v, 16);
        v += __shfl_xor(v, 32);
        if (quad == 0)
          atomicAdd(&L[bz * N + gn0 + wn * 64 + j * 16 + lm], v);
      }
    }
  }
#undef STG
#undef LD4A
#undef LD4B
#undef TILE8
}

// ---------------------------------------------------------------------------
// Round-9 128x128 kernel (ctx / out GEMMs: 512 blocks each keeps machine full)
// ---------------------------------------------------------------------------
template<int OUT_BF16, int HAS_BIAS, int EXP_COLSUM, int SPLIT3>
__global__ __launch_bounds__(256, 4)
void gemm_nt(const bf16_t* __restrict__ A, const bf16_t* __restrict__ Bt,
             void* __restrict__ Cv,
             const float* __restrict__ b0, const float* __restrict__ b1,
             const float* __restrict__ b2,
             float* __restrict__ L,
             int M, int N, int K, int ldC, float alpha,
             long sA, long sB, long sC,
             long co0, long co1, long co2,
             int mbShift, int ldTv, long sTv)
{
  __shared__ __align__(16) bf16_t smem[4 * 128 * 32];  // 32 KB
  bf16_t* As0 = smem;
  bf16_t* Bs0 = smem + 4096;
  bf16_t* As1 = smem + 8192;
  bf16_t* Bs1 = smem + 12288;

  const int bz = blockIdx.z;
  A  += bz * sA;
  Bt += bz * sB;

  int bx = blockIdx.x, by = blockIdx.y;
  {
    const int gx = gridDim.x, gy = gridDim.y;
    const int nb = gx * gy;
    if (((nb & 7) == 0) && ((gx & 3) == 0) && ((gy & 7) == 0)) {
      const int id   = bx + gx * by;
      const int xcd  = id & 7;
      const int o    = id >> 3;
      const int rows = gy >> 3;
      const int pw   = rows << 2;
      const int p    = o / pw;
      const int r    = o - p * pw;
      by = xcd * rows + (r >> 2);
      bx = (p << 2) + (r & 3);
    }
  }

  const int gn0 = bx * 128;
  const int m0  = by * 128;
  const int tid  = threadIdx.x;
  const int lane = tid & 63;
  const int wave = tid >> 6;
  const int wm   = (wave >> 1) * 64;
  const int wn   = (wave & 1) * 64;
  const int lm   = lane & 15;
  const int quad = lane >> 4;

  int n0 = gn0;
  int which = 0;
  bf16_t* Cb = (bf16_t*)Cv;
  float*  Cf = (float*)Cv;
  const float* bias = b0;
  if (SPLIT3) {
    which = gn0 >> 10;
    n0 = gn0 & 1023;
    Cb += (which == 0) ? co0 : (which == 1) ? co1 : co2;
    bias = (which == 0) ? b0 : (which == 1) ? b1 : b2;
  }

  const int srow   = lane >> 2;
  const int schunk = (lane & 3) * 8;
  const int gchunk = ((lane & 3) ^ ((srow >> 1) & 3)) * 8;
  const int fswz   = ((lm >> 1) & 3) * 8;

  floatx4 acc[4][4];
#pragma unroll
  for (int i = 0; i < 4; ++i)
#pragma unroll
    for (int j = 0; j < 4; ++j)
      acc[i][j] = (floatx4)(0.f);

  for (int kk = 0; kk < K; kk += 64) {
    __syncthreads();
#pragma unroll
    for (int t = 0; t < 2; ++t) {
      const int r = wave * 32 + t * 16 + srow;
      const long ar = (long)(m0  + r) * K + kk + gchunk;
      const long br = (long)(gn0 + r) * K + kk + gchunk;
      gl2lds16(A  + ar,      &As0[r * 32 + schunk]);
      gl2lds16(A  + ar + 32, &As1[r * 32 + schunk]);
      gl2lds16(Bt + br,      &Bs0[r * 32 + schunk]);
      gl2lds16(Bt + br + 32, &Bs1[r * 32 + schunk]);
    }
    __syncthreads();

    {
      bf16x8 af[4], bfr[4];
#pragma unroll
      for (int i = 0; i < 4; ++i)
        af[i] = *(const bf16x8*)&As0[(wm + i * 16 + lm) * 32 + ((quad * 8) ^ fswz)];
#pragma unroll
      for (int j = 0; j < 4; ++j)
        bfr[j] = *(const bf16x8*)&Bs0[(wn + j * 16 + lm) * 32 + ((quad * 8) ^ fswz)];
#pragma unroll
      for (int i = 0; i < 4; ++i)
#pragma unroll
        for (int j = 0; j < 4; ++j)
          acc[i][j] = __builtin_amdgcn_mfma_f32_16x16x32_bf16(af[i], bfr[j],
                                                              acc[i][j], 0, 0, 0);
    }
    {
      bf16x8 af[4], bfr[4];
#pragma unroll
      for (int i = 0; i < 4; ++i)
        af[i] = *(const bf16x8*)&As1[(wm + i * 16 + lm) * 32 + ((quad * 8) ^ fswz)];
#pragma unroll
      for (int j = 0; j < 4; ++j)
        bfr[j] = *(const bf16x8*)&Bs1[(wn + j * 16 + lm) * 32 + ((quad * 8) ^ fswz)];
#pragma unroll
      for (int i = 0; i < 4; ++i)
#pragma unroll
        for (int j = 0; j < 4; ++j)
          acc[i][j] = __builtin_amdgcn_mfma_f32_16x16x32_bf16(af[i], bfr[j],
                                                              acc[i][j], 0, 0, 0);
    }
  }

  if (SPLIT3 && which == 2) {
    __syncthreads();
    bf16_t* myT = smem + wave * (16 * 68);
    const int b  = m0 >> mbShift;
    const int s0 = m0 & ((1 << mbShift) - 1);
    const int r8 = lane >> 3;
    const int c8 = lane & 7;
#pragma unroll
    for (int j = 0; j < 4; ++j) {
      const float bv = HAS_BIAS ? bias[n0 + wn + j * 16 + lm] : 0.f;
#pragma unroll
      for (int i = 0; i < 4; ++i)
#pragma unroll
        for (int r = 0; r < 4; ++r)
          myT[lm * 68 + i * 16 + quad * 4 + r] = (bf16_t)(acc[i][j][r] + bv);
#pragma unroll
      for (int t = 0; t < 2; ++t) {
        const int nr = t * 8 + r8;
        const bf16x8 vv = *(const bf16x8*)&myT[nr * 68 + c8 * 8];
        *(bf16x8*)&Cb[(long)b * sTv + (long)(n0 + wn + j * 16 + nr) * ldTv
                      + s0 + wm + c8 * 8] = vv;
      }
    }
  } else if (OUT_BF16) {
    __syncthreads();
    bf16_t* myEp = smem + wave * (16 * 68);
    const int r8 = lane >> 3;
    const int c8 = lane & 7;
    float cs[4] = {0.f, 0.f, 0.f, 0.f};
#pragma unroll
    for (int i = 0; i < 4; ++i) {
#pragma unroll
      for (int j = 0; j < 4; ++j) {
        const float bv = HAS_BIAS ? bias[n0 + wn + j * 16 + lm] : 0.f;
#pragma unroll
        for (int r = 0; r < 4; ++r) {
          float v = alpha * acc[i][j][r];
          if (EXP_COLSUM) { v = __expf(v); cs[j] += v; }
          v += bv;
          myEp[(quad * 4 + r) * 68 + j * 16 + lm] = (bf16_t)v;
        }
      }
#pragma unroll
      for (int t = 0; t < 2; ++t) {
        const int row = t * 8 + r8;
        const bf16x8 vv = *(const bf16x8*)&myEp[row * 68 + c8 * 8];
        *(bf16x8*)&Cb[bz * sC + (long)(m0 + wm + i * 16 + row) * ldC
                      + n0 + wn + c8 * 8] = vv;
      }
    }
    if (EXP_COLSUM) {
#pragma unroll
      for (int j = 0; j < 4; ++j) {
        float v = cs[j];
        v += __shfl_xor(v, 16);
        v += __shfl_xor(v, 32);
        if (quad == 0)
          atomicAdd(&L[bz * N + gn0 + wn + j * 16 + lm], v);
      }
    }
  } else {
#pragma unroll
    for (int j = 0; j < 4; ++j) {
      const int cn = n0 + wn + j * 16 + lm;
      const float bv = HAS_BIAS ? bias[n0 + wn + j * 16 + lm] : 0.f;
#pragma unroll
      for (int i = 0; i < 4; ++i) {
        const int rbase = m0 + wm + i * 16 + quad * 4;
#pragma unroll
        for (int r = 0; r < 4; ++r)
          Cf[bz * sC + (long)(rbase + r) * ldC + cn] = alpha * acc[i][j][r] + bv;
      }
    }
  }
}

// ---------------------------------------------------------------------------
__global__ __launch_bounds__(256)
void prep(const float* __restrict__ x, bf16_t* __restrict__ Xb,
          const float* __restrict__ w0, const float* __restrict__ w1,
          const float* __restrict__ w2, const float* __restrict__ w3,
          bf16_t* __restrict__ outQKV, bf16_t* __restrict__ outO)
{
  __shared__ float tile[32][33];
  const int id = blockIdx.x;
  if (id < 8192) {
    const long i = ((long)id * 256 + threadIdx.x) * 4;
    const float4 v = *(const float4*)(x + i);
    struct alignas(8) B4 { bf16_t a, b, c, d; };
    B4 o; o.a = (bf16_t)v.x; o.b = (bf16_t)v.y; o.c = (bf16_t)v.z; o.d = (bf16_t)v.w;
    *(B4*)(Xb + i) = o;
  } else {
    const int t = id - 8192;
    const int z = t >> 10;
    const int bx = t & 31, by = (t >> 5) & 31;
    const float* in = (z == 0) ? w0 : (z == 1) ? w1 : (z == 2) ? w2 : w3;
    bf16_t* out = (z < 3) ? outQKV + (long)z * 1024 * 1024 : outO;
    const int c0 = bx * 32, r0 = by * 32;
    const int tx = threadIdx.x & 31;
    const int ty = threadIdx.x >> 5;
#pragma unroll
    for (int i = 0; i < 32; i += 8)
      tile[ty + i][tx] = in[(long)(r0 + ty + i) * 1024 + (c0 + tx)];
    __syncthreads();
#pragma unroll
    for (int i = 0; i < 32; i += 8)
      out[(long)(c0 + ty + i) * 1024 + (r0 + tx)] = (bf16_t)tile[tx][ty + i];
  }
}

// Vt[b][d][s] *= 1/L[b][s]
__global__ __launch_bounds__(256)
void scale_vt(bf16_t* __restrict__ Vt, const float* __restrict__ L, int S)
{
  const long base = ((long)blockIdx.x * blockDim.x + threadIdx.x) * 8;
  const int b  = (int)(base >> 21);
  const int s0 = (int)(base & (long)(S - 1));
  const float* Lb = L + b * S + s0;
  bf16x8 v = *(const bf16x8*)(Vt + base);
#pragma unroll
  for (int j = 0; j < 8; ++j)
    v[j] = (bf16_t)((float)v[j] / Lb[j]);
  *(bf16x8*)(Vt + base) = v;
}

// ---------------------------------------------------------------------------
extern "C" void kernel_launch(void* const* d_in, const int* in_sizes, int n_in,
                              void* d_out, int out_size, void* d_ws, size_t ws_size,
                              hipStream_t stream)
{
  const int Bz = 4, S = 2048, F = 1024, DK = 1024;
  const int M = Bz * S;

  const float* x  = (const float*)d_in[0];
  const float* Wq = (const float*)d_in[1];
  const float* bq = (const float*)d_in[2];
  const float* Wk = (const float*)d_in[3];
  const float* bk = (const float*)d_in[4];
  const float* Wv = (const float*)d_in[5];
  const float* bv = (const float*)d_in[6];
  const float* Wo = (const float*)d_in[7];
  const float* bo = (const float*)d_in[8];

  char* ws = (char*)d_ws;
  const size_t MB = 1ull << 20;
  bf16_t* Xb   = (bf16_t*)(ws + 0);
  bf16_t* Sc   = (bf16_t*)(ws + 0);
  bf16_t* Q    = (bf16_t*)(ws + 32 * MB);
  bf16_t* Ctx  = (bf16_t*)(ws + 32 * MB);
  bf16_t* Kb   = (bf16_t*)(ws + 48 * MB);
  bf16_t* Vt   = (bf16_t*)(ws + 64 * MB);
  bf16_t* WcatT= (bf16_t*)(ws + 80 * MB);
  float*  L    = (float*)(ws + 80 * MB);
  bf16_t* WoT  = (bf16_t*)(ws + 86 * MB);

  const long coQ = 16 * MB;
  const long coK = 24 * MB;
  const long coV = 32 * MB;

  prep<<<12288, 256, 0, stream>>>(x, Xb, Wq, Wk, Wv, Wo, WcatT, WoT);

  // merged Q/K/V projection (256^2 8-phase); V chunk stored transposed
  gemm256<1, 0, 1><<<dim3(3 * DK / 256, M / 256, 1), 512, 0, stream>>>(
      Xb, WcatT, (void*)ws, bq, bk, bv, nullptr, M, 3 * DK, F, DK, 1.f,
      0, 0, 0, coQ, coK, coV, 11, S, (long)DK * S);

  // P = exp(Q.K/sqrt(dk)); column sums -> L (256^2 8-phase, fused atomics)
  hipMemsetAsync(L, 0, (size_t)Bz * S * sizeof(float), stream);
  gemm256<0, 1, 0><<<dim3(S / 256, S / 256, Bz), 512, 0, stream>>>(
      Q, Kb, Sc, nullptr, nullptr, nullptr, L, S, S, DK, S, 0.03125f,
      (long)S * DK, (long)S * DK, (long)S * S, 0, 0, 0, 0, 0, 0);

  scale_vt<<<((long)Bz * DK * S / 8) / 256, 256, 0, stream>>>(Vt, L, S);

  // ctx = P @ (V/L)
  gemm_nt<1, 0, 0, 0><<<dim3(DK / 128, S / 128, Bz), 256, 0, stream>>>(
      Sc, Vt, Ctx, nullptr, nullptr, nullptr, nullptr, S, DK, S, DK, 1.f,
      (long)S * S, (long)S * DK, (long)S * DK, 0, 0, 0, 0, 0, 0);

  // out = ctx @ Wo + bo (fp32)
  gemm_nt<0, 1, 0, 0><<<dim3(F / 128, M / 128, 1), 256, 0, stream>>>(
      Ctx, WoT, d_out, bo, nullptr, nullptr, nullptr, M, F, DK, F, 1.f,
      0, 0, 0, 0, 0, 0, 0, 0, 0);
}

// Round 4
// 275.648 us; speedup vs baseline: 1.0633x; 1.0633x over previous
//
#include <hip/hip_runtime.h>
#include <hip/hip_bf16.h>
#include <cstdint>

typedef __bf16 bf16_t;
typedef __bf16 bf16x8 __attribute__((ext_vector_type(8)));
typedef float  floatx4 __attribute__((ext_vector_type(4)));

typedef const __attribute__((address_space(1))) unsigned int* gptr_t;
typedef __attribute__((address_space(3))) unsigned int* lptr_t;
typedef __attribute__((address_space(3))) const char* l3p;

static __device__ __forceinline__ void gl2lds16(const bf16_t* g, bf16_t* l) {
  __builtin_amdgcn_global_load_lds((gptr_t)g, (lptr_t)l, 16, 0, 0);
}

#define BAR()     asm volatile("s_barrier" ::: "memory")
#define VMW(NSTR) asm volatile("s_waitcnt vmcnt(" NSTR ")" ::: "memory")
#define LGKM0()   asm volatile("s_waitcnt lgkmcnt(0)" ::: "memory")
#define SB()      __builtin_amdgcn_sched_barrier(0)

// opaque LDS read: waitcnt pass inserts NO vmcnt before it and tracks no lgkm
// for it -> all read-vs-DMA ordering is ours (VMW/LGKM0 protocol below).
#define DSR(D, P, OFS) \
  asm volatile("ds_read_b128 %0, %1 offset:%2" : "=v"(D) : "v"(P), "i"(OFS))

// quadrant MFMA cluster: acc[F..F+3][J..J+1] over K=64 (16 MFMA), T5 wrap.
static __device__ __forceinline__ void mmQ(floatx4 (&acc)[8][4], int F, int J,
                                           const bf16x8 (&a)[8],
                                           const bf16x8 (&b)[4]) {
  __builtin_amdgcn_s_setprio(1);
#pragma unroll
  for (int f = 0; f < 4; ++f)
#pragma unroll
    for (int j = 0; j < 2; ++j) {
      acc[F + f][J + j] = __builtin_amdgcn_mfma_f32_16x16x32_bf16(
          a[f], b[j], acc[F + f][J + j], 0, 0, 0);
      acc[F + f][J + j] = __builtin_amdgcn_mfma_f32_16x16x32_bf16(
          a[4 + f], b[2 + j], acc[F + f][J + j], 0, 0, 0);
    }
  __builtin_amdgcn_s_setprio(0);
}

// ---------------------------------------------------------------------------
// ROUND-13: 256x256 8-phase GEMM with INLINE-ASM ds_reads (opaque to the
// waitcnt pass). Rounds 10-12 all ran at the degenerate 2-phase rate (666 TF,
// 1428 cy/phase = +~900cy/phase over m201's 528): signature of a compiler
// vmcnt inserted before each phase's ds_reads to order them against in-flight
// global_load_lds DMA. Fix: asm ds_read_b128 (compiler inserts no waits);
// consumption is SAME-PHASE (m201 scheme): per K-tile 4 phases, each = one
// output quadrant x K=64:
//   ph0: read a0(8)+b0(4); STG other.Ak1(t+1); BAR; lgkm0; mm(f0-3,j0-1); BAR
//   ph1: read a1(8);       STG other.Bk1(t+1); BAR; lgkm0; mm(f4-7,j0-1); BAR
//   ph2: read b1(4);       STG cur.Ak0 (t+2);  BAR; lgkm0; mm(f0-3,j2-3); BAR
//   ph3:                   STG cur.Bk0 (t+2);  BAR;        mm(f4-7,j2-3);
//                                              VMW(4); BAR
// Waits (all manual):
//  * lgkmcnt(0) after BAR covers only this wave's just-issued asm reads
//    (the ONLY lgkm ops in the loop); sched_barrier(0) after it (rule #18).
//  * ONE VMW(4) per tile at ph3-end BEFORE the barrier: confirms this wave's
//    slices of tile t+1's buffer (youngest needed = other.Bk1 staged ph1(t);
//    exactly 4 loads issued after it: ph2+ph3 stages). Every wave executes
//    VMW then BAR -> after BAR, ALL waves' slices landed -> ph0(t+1) reads
//    (issued pre-BAR1 of next phase) are race-free. Last tile pair: VMW(0)
//    at nt-2 (its ph2/ph3 stages are gated off, so only 0 loads follow Bk1).
//  * Overwrite-vs-read: STG(X) issued in the first phase AFTER the barrier
//    that follows X's last reader phase (A last read ph1 -> staged ph2;
//    B last read ph2 -> staged ph3; other-buf staged ph0/ph1). Checked all 4.
// Geometry: 8 waves (2Mx4N), per-wave 128x64 (acc[8][4]), BK=64 as two K=32
// halves in separate arrays, XOR chunk swizzle, panel-walking XCD swizzle.
// ---------------------------------------------------------------------------
template<int HAS_BIAS, int EXP_COLSUM, int SPLIT3>
__global__ __launch_bounds__(512, 2)
void gemm256(const bf16_t* __restrict__ A, const bf16_t* __restrict__ Bt,
             void* __restrict__ Cv,
             const float* __restrict__ b0v, const float* __restrict__ b1v,
             const float* __restrict__ b2v,
             float* __restrict__ L,
             int M, int N, int K, int ldC, float alpha,
             long sA, long sB, long sC,
             long co0, long co1, long co2,
             int mbShift, int ldTv, long sTv)
{
  __shared__ __align__(16) bf16_t sA0k0[8192];
  __shared__ __align__(16) bf16_t sA0k1[8192];
  __shared__ __align__(16) bf16_t sB0k0[8192];
  __shared__ __align__(16) bf16_t sB0k1[8192];
  __shared__ __align__(16) bf16_t sA1k0[8192];
  __shared__ __align__(16) bf16_t sA1k1[8192];
  __shared__ __align__(16) bf16_t sB1k0[8192];
  __shared__ __align__(16) bf16_t sB1k1[8192];

  const int bz = blockIdx.z;
  A  += bz * sA;
  Bt += bz * sB;

  // XCD-aware swizzle v2 (panel-walking)
  int bx = blockIdx.x, by = blockIdx.y;
  {
    const int gx = gridDim.x, gy = gridDim.y;
    const int nb = gx * gy;
    if (((nb & 7) == 0) && ((gx & 3) == 0) && ((gy & 7) == 0)) {
      const int id   = bx + gx * by;
      const int xcd  = id & 7;
      const int o    = id >> 3;
      const int rows = gy >> 3;
      const int pw   = rows << 2;
      const int p    = o / pw;
      const int r    = o - p * pw;
      by = xcd * rows + (r >> 2);
      bx = (p << 2) + (r & 3);
    }
  }

  const int gn0 = bx * 256;
  const int m0  = by * 256;
  const int tid  = threadIdx.x;
  const int lane = tid & 63;
  const int wave = tid >> 6;
  const int wm   = wave >> 2;      // 0..1  (M half)
  const int wn   = wave & 3;       // 0..3  (N quarter)
  const int lm   = lane & 15;
  const int quad = lane >> 4;

  int n0 = gn0, which = 0;
  bf16_t* Cb = (bf16_t*)Cv;
  const float* bias = b0v;
  if (SPLIT3) {
    which = gn0 >> 10;
    n0 = gn0 & 1023;
    Cb += (which == 0) ? co0 : (which == 1) ? co1 : co2;
    bias = (which == 0) ? b0v : (which == 1) ? b1v : b2v;
  }

  // staging: thread tid -> row tid>>2 (+128 for 2nd load), LDS chunk tid&3;
  // global chunk pre-swizzled with row bits 1-2 (involution).
  const int srow = tid >> 2;
  const int scol = ((tid ^ (tid >> 3)) & 3) * 8;
  const bf16_t* pA = A  + (long)(m0  + srow) * K + scol;
  const bf16_t* pB = Bt + (long)(gn0 + srow) * K + scol;

  const int nt = K >> 6;            // K-tiles of 64 (even, >= 4)

  // fragment-read base byte offsets (chunk XOR matches staging involution)
  const int csz  = ((quad ^ (lm >> 1)) & 3) * 16;
  const int arow = (wm * 128 + lm) * 64 + csz;   // A quadrant mh=0, f=0
  const int brow = (wn * 64  + lm) * 64 + csz;   // B j=0

#define STG(DST, GP) do { \
    gl2lds16((GP), &DST[tid * 8]); \
    gl2lds16((GP) + (long)128 * K, &DST[tid * 8 + 4096]); } while (0)

#define RDA0(AK0, AK1) do { \
    l3p _p0 = (l3p)(AK0) + arow; l3p _p1 = (l3p)(AK1) + arow; \
    DSR(a0[0], _p0, 0);    DSR(a0[1], _p0, 1024); \
    DSR(a0[2], _p0, 2048); DSR(a0[3], _p0, 3072); \
    DSR(a0[4], _p1, 0);    DSR(a0[5], _p1, 1024); \
    DSR(a0[6], _p1, 2048); DSR(a0[7], _p1, 3072); } while (0)

#define RDA1(AK0, AK1) do { \
    l3p _p0 = (l3p)(AK0) + arow; l3p _p1 = (l3p)(AK1) + arow; \
    DSR(a1[0], _p0, 4096); DSR(a1[1], _p0, 5120); \
    DSR(a1[2], _p0, 6144); DSR(a1[3], _p0, 7168); \
    DSR(a1[4], _p1, 4096); DSR(a1[5], _p1, 5120); \
    DSR(a1[6], _p1, 6144); DSR(a1[7], _p1, 7168); } while (0)

#define RDB0(BK0, BK1) do { \
    l3p _p0 = (l3p)(BK0) + brow; l3p _p1 = (l3p)(BK1) + brow; \
    DSR(b0[0], _p0, 0); DSR(b0[1], _p0, 1024); \
    DSR(b0[2], _p1, 0); DSR(b0[3], _p1, 1024); } while (0)

#define RDB1(BK0, BK1) do { \
    l3p _p0 = (l3p)(BK0) + brow; l3p _p1 = (l3p)(BK1) + brow; \
    DSR(b1[0], _p0, 2048); DSR(b1[1], _p0, 3072); \
    DSR(b1[2], _p1, 2048); DSR(b1[3], _p1, 3072); } while (0)

#define TILE4(AK0, AK1, BK0, BK1, OAK1, OBK1, T, S01, S23, WS, DO_W) do { \
    /* ph0: quadrant (f0-3, j0-1) */ \
    RDA0(AK0, AK1); RDB0(BK0, BK1); \
    if (S01) STG(OAK1, pA + ((T) + 1) * 64 + 32); \
    SB(); BAR(); LGKM0(); SB(); \
    mmQ(acc, 0, 0, a0, b0); \
    SB(); BAR(); \
    /* ph1: (f4-7, j0-1) */ \
    RDA1(AK0, AK1); \
    if (S01) STG(OBK1, pB + ((T) + 1) * 64 + 32); \
    SB(); BAR(); LGKM0(); SB(); \
    mmQ(acc, 4, 0, a1, b0); \
    SB(); BAR(); \
    /* ph2: (f0-3, j2-3) */ \
    RDB1(BK0, BK1); \
    if (S23) STG(AK0, pA + ((T) + 2) * 64); \
    SB(); BAR(); LGKM0(); SB(); \
    mmQ(acc, 0, 2, a0, b1); \
    SB(); BAR(); \
    /* ph3: (f4-7, j2-3); tile-t+1 buffer confirmation */ \
    if (S23) STG(BK0, pB + ((T) + 2) * 64); \
    SB(); BAR(); \
    mmQ(acc, 4, 2, a1, b1); \
    SB(); if (DO_W) VMW(WS); BAR(); \
  } while (0)

  floatx4 acc[8][4];
#pragma unroll
  for (int f = 0; f < 8; ++f)
#pragma unroll
    for (int j = 0; j < 4; ++j)
      acc[f][j] = (floatx4)(0.f);

  bf16x8 a0[8], a1[8], b0[4], b1[4];

  // prologue: tile0's 4 halves then tile1's k0 halves (12 loads);
  // VMW(4) -> the 8 buf0 loads landed (4 newest = buf1.k0 may fly).
  STG(sA0k0, pA);
  STG(sB0k0, pB);
  STG(sA0k1, pA + 32);
  STG(sB0k1, pB + 32);
  STG(sA1k0, pA + 64);
  STG(sB1k0, pB + 64);
  VMW("4"); BAR();

  const int npair = nt >> 1;
  for (int p = 0; p < npair - 1; ++p) {
    const int t0 = 2 * p;
    TILE4(sA0k0, sA0k1, sB0k0, sB0k1, sA1k1, sB1k1, t0,     1, 1, "4", 1);
    TILE4(sA1k0, sA1k1, sB1k0, sB1k1, sA0k1, sB0k1, t0 + 1, 1, 1, "4", 1);
  }
  // tail: tile nt-2 stages only t+1's k1 halves; VMW(0) confirms them.
  TILE4(sA0k0, sA0k1, sB0k0, sB0k1, sA1k1, sB1k1, nt - 2, 1, 0, "0", 1);
  TILE4(sA1k0, sA1k1, sB1k0, sB1k1, sA0k1, sB0k1, nt - 1, 0, 0, "0", 0);

  // ---------------- epilogue (C/D layout: col=lm, row=quad*4+r) ------------
  __syncthreads();
  const int r8 = lane >> 3;
  const int c8 = lane & 7;

  if (SPLIT3 && which == 2) {
    // transposed store: Vt[b][d][s]; per-wave scratch [16][144] = 2304 elems
    bf16_t* myT = (wave < 3) ? (sA0k0 + wave * 2304)
                : (wave < 6) ? (sA0k1 + (wave - 3) * 2304)
                             : (sB0k0 + (wave - 6) * 2304);
    const int b  = m0 >> mbShift;
    const int s0 = m0 & ((1 << mbShift) - 1);
#pragma unroll
    for (int j = 0; j < 4; ++j) {
      const float bv = HAS_BIAS ? bias[n0 + wn * 64 + j * 16 + lm] : 0.f;
#pragma unroll
      for (int f = 0; f < 8; ++f)
#pragma unroll
        for (int r = 0; r < 4; ++r)
          myT[lm * 144 + f * 16 + quad * 4 + r] = (bf16_t)(acc[f][j][r] + bv);
      // per-wave region + in-order DS pipe: no barrier needed
#pragma unroll
      for (int t2 = 0; t2 < 4; ++t2) {
        const int dr = (t2 & 1) * 8 + r8;
        const int ck = (t2 >> 1) * 8 + c8;
        const bf16x8 vv = *(const bf16x8*)&myT[dr * 144 + ck * 8];
        *(bf16x8*)&Cb[(long)b * sTv + (long)(n0 + wn * 64 + j * 16 + dr) * ldTv
                      + s0 + wm * 128 + ck * 8] = vv;
      }
    }
  } else {
    // per-wave scratch [16][68] = 1088 elems
    bf16_t* myEp = (wave < 7) ? (sA0k0 + wave * 1088) : sA0k1;
    float csum[4] = {0.f, 0.f, 0.f, 0.f};
    float bv[4];
#pragma unroll
    for (int j = 0; j < 4; ++j)
      bv[j] = HAS_BIAS ? bias[n0 + wn * 64 + j * 16 + lm] : 0.f;
#pragma unroll
    for (int f = 0; f < 8; ++f) {
#pragma unroll
      for (int j = 0; j < 4; ++j)
#pragma unroll
        for (int r = 0; r < 4; ++r) {
          float v = acc[f][j][r];
          if (EXP_COLSUM) { v = __expf(alpha * v); csum[j] += v; }
          v += bv[j];
          myEp[(quad * 4 + r) * 68 + j * 16 + lm] = (bf16_t)v;
        }
#pragma unroll
      for (int t2 = 0; t2 < 2; ++t2) {
        const int row = t2 * 8 + r8;
        const bf16x8 vv = *(const bf16x8*)&myEp[row * 68 + c8 * 8];
        *(bf16x8*)&Cb[bz * sC + (long)(m0 + wm * 128 + f * 16 + row) * ldC
                      + n0 + wn * 64 + c8 * 8] = vv;
      }
    }
    if (EXP_COLSUM) {
#pragma unroll
      for (int j = 0; j < 4; ++j) {
        float v = csum[j];
        v += __shfl_xor(v, 16);
        v += __shfl_xor(v, 32);
        if (quad == 0)
          atomicAdd(&L[bz * N + gn0 + wn * 64 + j * 16 + lm], v);
      }
    }
  }
#undef STG
#undef RDA0
#undef RDA1
#undef RDB0
#undef RDB1
#undef TILE4
}

// ---------------------------------------------------------------------------
// Round-9 128x128 kernel (ctx / out GEMMs: 512 blocks each keeps machine full)
// ---------------------------------------------------------------------------
template<int OUT_BF16, int HAS_BIAS, int EXP_COLSUM, int SPLIT3>
__global__ __launch_bounds__(256, 4)
void gemm_nt(const bf16_t* __restrict__ A, const bf16_t* __restrict__ Bt,
             void* __restrict__ Cv,
             const float* __restrict__ b0, const float* __restrict__ b1,
             const float* __restrict__ b2,
             float* __restrict__ L,
             int M, int N, int K, int ldC, float alpha,
             long sA, long sB, long sC,
             long co0, long co1, long co2,
             int mbShift, int ldTv, long sTv)
{
  __shared__ __align__(16) bf16_t smem[4 * 128 * 32];  // 32 KB
  bf16_t* As0 = smem;
  bf16_t* Bs0 = smem + 4096;
  bf16_t* As1 = smem + 8192;
  bf16_t* Bs1 = smem + 12288;

  const int bz = blockIdx.z;
  A  += bz * sA;
  Bt += bz * sB;

  int bx = blockIdx.x, by = blockIdx.y;
  {
    const int gx = gridDim.x, gy = gridDim.y;
    const int nb = gx * gy;
    if (((nb & 7) == 0) && ((gx & 3) == 0) && ((gy & 7) == 0)) {
      const int id   = bx + gx * by;
      const int xcd  = id & 7;
      const int o    = id >> 3;
      const int rows = gy >> 3;
      const int pw   = rows << 2;
      const int p    = o / pw;
      const int r    = o - p * pw;
      by = xcd * rows + (r >> 2);
      bx = (p << 2) + (r & 3);
    }
  }

  const int gn0 = bx * 128;
  const int m0  = by * 128;
  const int tid  = threadIdx.x;
  const int lane = tid & 63;
  const int wave = tid >> 6;
  const int wm   = (wave >> 1) * 64;
  const int wn   = (wave & 1) * 64;
  const int lm   = lane & 15;
  const int quad = lane >> 4;

  int n0 = gn0;
  int which = 0;
  bf16_t* Cb = (bf16_t*)Cv;
  float*  Cf = (float*)Cv;
  const float* bias = b0;
  if (SPLIT3) {
    which = gn0 >> 10;
    n0 = gn0 & 1023;
    Cb += (which == 0) ? co0 : (which == 1) ? co1 : co2;
    bias = (which == 0) ? b0 : (which == 1) ? b1 : b2;
  }

  const int srow   = lane >> 2;
  const int schunk = (lane & 3) * 8;
  const int gchunk = ((lane & 3) ^ ((srow >> 1) & 3)) * 8;
  const int fswz   = ((lm >> 1) & 3) * 8;

  floatx4 acc[4][4];
#pragma unroll
  for (int i = 0; i < 4; ++i)
#pragma unroll
    for (int j = 0; j < 4; ++j)
      acc[i][j] = (floatx4)(0.f);

  for (int kk = 0; kk < K; kk += 64) {
    __syncthreads();
#pragma unroll
    for (int t = 0; t < 2; ++t) {
      const int r = wave * 32 + t * 16 + srow;
      const long ar = (long)(m0  + r) * K + kk + gchunk;
      const long br = (long)(gn0 + r) * K + kk + gchunk;
      gl2lds16(A  + ar,      &As0[r * 32 + schunk]);
      gl2lds16(A  + ar + 32, &As1[r * 32 + schunk]);
      gl2lds16(Bt + br,      &Bs0[r * 32 + schunk]);
      gl2lds16(Bt + br + 32, &Bs1[r * 32 + schunk]);
    }
    __syncthreads();

    {
      bf16x8 af[4], bfr[4];
#pragma unroll
      for (int i = 0; i < 4; ++i)
        af[i] = *(const bf16x8*)&As0[(wm + i * 16 + lm) * 32 + ((quad * 8) ^ fswz)];
#pragma unroll
      for (int j = 0; j < 4; ++j)
        bfr[j] = *(const bf16x8*)&Bs0[(wn + j * 16 + lm) * 32 + ((quad * 8) ^ fswz)];
#pragma unroll
      for (int i = 0; i < 4; ++i)
#pragma unroll
        for (int j = 0; j < 4; ++j)
          acc[i][j] = __builtin_amdgcn_mfma_f32_16x16x32_bf16(af[i], bfr[j],
                                                              acc[i][j], 0, 0, 0);
    }
    {
      bf16x8 af[4], bfr[4];
#pragma unroll
      for (int i = 0; i < 4; ++i)
        af[i] = *(const bf16x8*)&As1[(wm + i * 16 + lm) * 32 + ((quad * 8) ^ fswz)];
#pragma unroll
      for (int j = 0; j < 4; ++j)
        bfr[j] = *(const bf16x8*)&Bs1[(wn + j * 16 + lm) * 32 + ((quad * 8) ^ fswz)];
#pragma unroll
      for (int i = 0; i < 4; ++i)
#pragma unroll
        for (int j = 0; j < 4; ++j)
          acc[i][j] = __builtin_amdgcn_mfma_f32_16x16x32_bf16(af[i], bfr[j],
                                                              acc[i][j], 0, 0, 0);
    }
  }

  if (SPLIT3 && which == 2) {
    __syncthreads();
    bf16_t* myT = smem + wave * (16 * 68);
    const int b  = m0 >> mbShift;
    const int s0 = m0 & ((1 << mbShift) - 1);
    const int r8 = lane >> 3;
    const int c8 = lane & 7;
#pragma unroll
    for (int j = 0; j < 4; ++j) {
      const float bv = HAS_BIAS ? bias[n0 + wn + j * 16 + lm] : 0.f;
#pragma unroll
      for (int i = 0; i < 4; ++i)
#pragma unroll
        for (int r = 0; r < 4; ++r)
          myT[lm * 68 + i * 16 + quad * 4 + r] = (bf16_t)(acc[i][j][r] + bv);
#pragma unroll
      for (int t = 0; t < 2; ++t) {
        const int nr = t * 8 + r8;
        const bf16x8 vv = *(const bf16x8*)&myT[nr * 68 + c8 * 8];
        *(bf16x8*)&Cb[(long)b * sTv + (long)(n0 + wn + j * 16 + nr) * ldTv
                      + s0 + wm + c8 * 8] = vv;
      }
    }
  } else if (OUT_BF16) {
    __syncthreads();
    bf16_t* myEp = smem + wave * (16 * 68);
    const int r8 = lane >> 3;
    const int c8 = lane & 7;
    float cs[4] = {0.f, 0.f, 0.f, 0.f};
#pragma unroll
    for (int i = 0; i < 4; ++i) {
#pragma unroll
      for (int j = 0; j < 4; ++j) {
        const float bv = HAS_BIAS ? bias[n0 + wn + j * 16 + lm] : 0.f;
#pragma unroll
        for (int r = 0; r < 4; ++r) {
          float v = alpha * acc[i][j][r];
          if (EXP_COLSUM) { v = __expf(v); cs[j] += v; }
          v += bv;
          myEp[(quad * 4 + r) * 68 + j * 16 + lm] = (bf16_t)v;
        }
      }
#pragma unroll
      for (int t = 0; t < 2; ++t) {
        const int row = t * 8 + r8;
        const bf16x8 vv = *(const bf16x8*)&myEp[row * 68 + c8 * 8];
        *(bf16x8*)&Cb[bz * sC + (long)(m0 + wm + i * 16 + row) * ldC
                      + n0 + wn + c8 * 8] = vv;
      }
    }
    if (EXP_COLSUM) {
#pragma unroll
      for (int j = 0; j < 4; ++j) {
        float v = cs[j];
        v += __shfl_xor(v, 16);
        v += __shfl_xor(v, 32);
        if (quad == 0)
          atomicAdd(&L[bz * N + gn0 + wn + j * 16 + lm], v);
      }
    }
  } else {
#pragma unroll
    for (int j = 0; j < 4; ++j) {
      const int cn = n0 + wn + j * 16 + lm;
      const float bv = HAS_BIAS ? bias[n0 + wn + j * 16 + lm] : 0.f;
#pragma unroll
      for (int i = 0; i < 4; ++i) {
        const int rbase = m0 + wm + i * 16 + quad * 4;
#pragma unroll
        for (int r = 0; r < 4; ++r)
          Cf[bz * sC + (long)(rbase + r) * ldC + cn] = alpha * acc[i][j][r] + bv;
      }
    }
  }
}

// ---------------------------------------------------------------------------
__global__ __launch_bounds__(256)
void prep(const float* __restrict__ x, bf16_t* __restrict__ Xb,
          const float* __restrict__ w0, const float* __restrict__ w1,
          const float* __restrict__ w2, const float* __restrict__ w3,
          bf16_t* __restrict__ outQKV, bf16_t* __restrict__ outO)
{
  __shared__ float tile[32][33];
  const int id = blockIdx.x;
  if (id < 8192) {
    const long i = ((long)id * 256 + threadIdx.x) * 4;
    const float4 v = *(const float4*)(x + i);
    struct alignas(8) B4 { bf16_t a, b, c, d; };
    B4 o; o.a = (bf16_t)v.x; o.b = (bf16_t)v.y; o.c = (bf16_t)v.z; o.d = (bf16_t)v.w;
    *(B4*)(Xb + i) = o;
  } else {
    const int t = id - 8192;
    const int z = t >> 10;
    const int bx = t & 31, by = (t >> 5) & 31;
    const float* in = (z == 0) ? w0 : (z == 1) ? w1 : (z == 2) ? w2 : w3;
    bf16_t* out = (z < 3) ? outQKV + (long)z * 1024 * 1024 : outO;
    const int c0 = bx * 32, r0 = by * 32;
    const int tx = threadIdx.x & 31;
    const int ty = threadIdx.x >> 5;
#pragma unroll
    for (int i = 0; i < 32; i += 8)
      tile[ty + i][tx] = in[(long)(r0 + ty + i) * 1024 + (c0 + tx)];
    __syncthreads();
#pragma unroll
    for (int i = 0; i < 32; i += 8)
      out[(long)(c0 + ty + i) * 1024 + (r0 + tx)] = (bf16_t)tile[tx][ty + i];
  }
}

// Vt[b][d][s] *= 1/L[b][s]
__global__ __launch_bounds__(256)
void scale_vt(bf16_t* __restrict__ Vt, const float* __restrict__ L, int S)
{
  const long base = ((long)blockIdx.x * blockDim.x + threadIdx.x) * 8;
  const int b  = (int)(base >> 21);
  const int s0 = (int)(base & (long)(S - 1));
  const float* Lb = L + b * S + s0;
  bf16x8 v = *(const bf16x8*)(Vt + base);
#pragma unroll
  for (int j = 0; j < 8; ++j)
    v[j] = (bf16_t)((float)v[j] / Lb[j]);
  *(bf16x8*)(Vt + base) = v;
}

// ---------------------------------------------------------------------------
extern "C" void kernel_launch(void* const* d_in, const int* in_sizes, int n_in,
                              void* d_out, int out_size, void* d_ws, size_t ws_size,
                              hipStream_t stream)
{
  const int Bz = 4, S = 2048, F = 1024, DK = 1024;
  const int M = Bz * S;

  const float* x  = (const float*)d_in[0];
  const float* Wq = (const float*)d_in[1];
  const float* bq = (const float*)d_in[2];
  const float* Wk = (const float*)d_in[3];
  const float* bk = (const float*)d_in[4];
  const float* Wv = (const float*)d_in[5];
  const float* bv = (const float*)d_in[6];
  const float* Wo = (const float*)d_in[7];
  const float* bo = (const float*)d_in[8];

  char* ws = (char*)d_ws;
  const size_t MB = 1ull << 20;
  bf16_t* Xb   = (bf16_t*)(ws + 0);
  bf16_t* Sc   = (bf16_t*)(ws + 0);
  bf16_t* Q    = (bf16_t*)(ws + 32 * MB);
  bf16_t* Ctx  = (bf16_t*)(ws + 32 * MB);
  bf16_t* Kb   = (bf16_t*)(ws + 48 * MB);
  bf16_t* Vt   = (bf16_t*)(ws + 64 * MB);
  bf16_t* WcatT= (bf16_t*)(ws + 80 * MB);
  float*  L    = (float*)(ws + 80 * MB);
  bf16_t* WoT  = (bf16_t*)(ws + 86 * MB);

  const long coQ = 16 * MB;
  const long coK = 24 * MB;
  const long coV = 32 * MB;

  prep<<<12288, 256, 0, stream>>>(x, Xb, Wq, Wk, Wv, Wo, WcatT, WoT);

  // merged Q/K/V projection (256^2 asm-read 8-phase); V stored transposed
  gemm256<1, 0, 1><<<dim3(3 * DK / 256, M / 256, 1), 512, 0, stream>>>(
      Xb, WcatT, (void*)ws, bq, bk, bv, nullptr, M, 3 * DK, F, DK, 1.f,
      0, 0, 0, coQ, coK, coV, 11, S, (long)DK * S);

  // P = exp(Q.K/sqrt(dk)); column sums -> L
  hipMemsetAsync(L, 0, (size_t)Bz * S * sizeof(float), stream);
  gemm256<0, 1, 0><<<dim3(S / 256, S / 256, Bz), 512, 0, stream>>>(
      Q, Kb, Sc, nullptr, nullptr, nullptr, L, S, S, DK, S, 0.03125f,
      (long)S * DK, (long)S * DK, (long)S * S, 0, 0, 0, 0, 0, 0);

  scale_vt<<<((long)Bz * DK * S / 8) / 256, 256, 0, stream>>>(Vt, L, S);

  // ctx = P @ (V/L)
  gemm_nt<1, 0, 0, 0><<<dim3(DK / 128, S / 128, Bz), 256, 0, stream>>>(
      Sc, Vt, Ctx, nullptr, nullptr, nullptr, nullptr, S, DK, S, DK, 1.f,
      (long)S * S, (long)S * DK, (long)S * DK, 0, 0, 0, 0, 0, 0);

  // out = ctx @ Wo + bo (fp32)
  gemm_nt<0, 1, 0, 0><<<dim3(F / 128, M / 128, 1), 256, 0, stream>>>(
      Ctx, WoT, d_out, bo, nullptr, nullptr, nullptr, M, F, DK, F, 1.f,
      0, 0, 0, 0, 0, 0, 0, 0, 0);
}